// Round 8
// baseline (237.972 us; speedup 1.0000x reference)
//
#include <hip/hip_runtime.h>
#include <hip/hip_bf16.h>

#define DEV __device__ __forceinline__

typedef unsigned short u16;
typedef unsigned int u32;
typedef __attribute__((ext_vector_type(4))) float f32x4;
typedef __attribute__((ext_vector_type(16))) float f32x16;
typedef __attribute__((ext_vector_type(8))) __bf16 bf16x8;
typedef __attribute__((ext_vector_type(8))) u16 u16x8;
typedef __attribute__((ext_vector_type(4))) u16 u16x4;
typedef __attribute__((ext_vector_type(4))) u32 u32x4;

// 0.125 * log2(e): folded into Wq/bq so S comes out of QK^T pre-scaled for exp2
#define CSCALE 0.18033688011112042f

DEV u16 f2bf(float f) {
    u32 u = __builtin_bit_cast(u32, f);
    u32 r = (u + 0x7fffu + ((u >> 16) & 1u)) >> 16;
    return (u16)r;
}

DEV u16 f2bf_fast(float f) {
    u32 u = __builtin_bit_cast(u32, f);
    return (u16)((u + 0x8000u) >> 16);
}

DEV float fastrcp(float x) {
#if __has_builtin(__builtin_amdgcn_rcpf)
    return __builtin_amdgcn_rcpf(x);
#else
    return 1.0f / x;
#endif
}

DEV u32 cvtpk_bf16(float lo, float hi) {
    u32 r;
    asm("v_cvt_pk_bf16_f32 %0, %1, %2" : "=v"(r) : "v"(lo), "v"(hi));
    return r;
}

DEV void plswap(u32& a, u32& b) {
    asm volatile("v_permlane32_swap_b32 %0, %1" : "+v"(a), "+v"(b));
}

DEV void gload_lds16(const void* g, void* l) {
    void* gg = const_cast<void*>(g);
    __builtin_amdgcn_global_load_lds(
        (const __attribute__((address_space(1))) void*)gg,
        (__attribute__((address_space(3))) void*)l,
        16, 0, 0);
}

DEV f32x16 mfma32(bf16x8 a, bf16x8 b, f32x16 c) {
    return __builtin_amdgcn_mfma_f32_32x32x16_bf16(a, b, c, 0, 0, 0);
}

// ---------------- f32 -> bf16 conversion (optional scale) ----------------
__global__ void cvt_f32_bf16(const float* __restrict__ in, u16* __restrict__ out,
                             int n4, float scale) {
    int i = blockIdx.x * blockDim.x + threadIdx.x;
    if (i < n4) {
        float4 v = ((const float4*)in)[i];
        u16x4 o;
        o[0] = f2bf(v.x * scale); o[1] = f2bf(v.y * scale);
        o[2] = f2bf(v.z * scale); o[3] = f2bf(v.w * scale);
        ((u16x4*)out)[i] = o;
    }
}

// ---------------- concat bias [bq*C | bk | bv] -> f32[3072] ----------------
__global__ void build_bias(const float* __restrict__ bq, const float* __restrict__ bk,
                           const float* __restrict__ bv, float* __restrict__ o) {
    int i = blockIdx.x * blockDim.x + threadIdx.x;
    if (i < 3072) {
        float v;
        if (i < 1024) v = bq[i] * CSCALE;
        else if (i < 2048) v = bk[i - 1024];
        else v = bv[i - 2048];
        o[i] = v;
    }
}

// ---------------- GEMM: C[M,N] = A[M,K] * B[N,K]^T + bias ----------------
// 1D grid, XCD-chunked swizzle: xcd = id&7 owns bn columns [xcd*bnPerXcd, ...).
template<int F32OUT>
__global__ __launch_bounds__(256) void gemm_bt(
    const u16* __restrict__ A, const u16* __restrict__ B,
    const float* __restrict__ bias, void* __restrict__ Cv,
    int K, int ldc, int bnPerXcd)
{
    __shared__ u16 As[128 * 64];
    __shared__ u16 Bs[128 * 64];
    const int t = threadIdx.x;
    const int lane = t & 63;
    const int w = t >> 6;
    const int wm = w >> 1, wn = w & 1;
    const int id = (int)blockIdx.x;
    const int xcd = id & 7, r = id >> 3;
    const int bm = (r & 63) * 128;
    const int bn = (xcd * bnPerXcd + (r >> 6)) * 128;
    const int lr = lane & 15;
    const int lg = lane >> 4;

    f32x4 acc[4][4] = {};

    for (int k0 = 0; k0 < K; k0 += 64) {
        #pragma unroll
        for (int i = 0; i < 4; ++i) {
            int off = (t + i * 256) * 16;
            int row = off >> 7;
            int colb = off & 127;
            gload_lds16((const char*)A + ((size_t)(bm + row) * K + k0) * 2 + colb,
                        (char*)As + off);
            gload_lds16((const char*)B + ((size_t)(bn + row) * K + k0) * 2 + colb,
                        (char*)Bs + off);
        }
        __syncthreads();
        #pragma unroll
        for (int kk = 0; kk < 2; ++kk) {
            bf16x8 af[4], bfr[4];
            #pragma unroll
            for (int m = 0; m < 4; ++m)
                af[m] = *(const bf16x8*)&As[(wm * 64 + m * 16 + lr) * 64 + kk * 32 + lg * 8];
            #pragma unroll
            for (int n = 0; n < 4; ++n)
                bfr[n] = *(const bf16x8*)&Bs[(wn * 64 + n * 16 + lr) * 64 + kk * 32 + lg * 8];
            #pragma unroll
            for (int m = 0; m < 4; ++m)
                #pragma unroll
                for (int n = 0; n < 4; ++n)
                    acc[m][n] = __builtin_amdgcn_mfma_f32_16x16x32_bf16(af[m], bfr[n], acc[m][n], 0, 0, 0);
        }
        __syncthreads();
    }

    #pragma unroll
    for (int n = 0; n < 4; ++n) {
        int col = bn + wn * 64 + n * 16 + lr;
        float bv = bias[col];
        #pragma unroll
        for (int m = 0; m < 4; ++m) {
            int row0 = bm + wm * 64 + m * 16 + lg * 4;
            #pragma unroll
            for (int r2 = 0; r2 < 4; ++r2) {
                float v = acc[m][n][r2] + bv;
                size_t idx = (size_t)(row0 + r2) * ldc + col;
                if (F32OUT) ((float*)Cv)[idx] = v;
                else        ((u16*)Cv)[idx] = f2bf(v);
            }
        }
    }
}

// ---------------- causal flash attention, v8 ----------------
// Single 128-row q-tile per block, 1024 blocks, 4 blocks/CU (16 waves/CU).
// Heavy-first dispatch (slot 0 = q0 max) + XCD head-grouping.
// No-max softmax; BUF-static unroll-2; wave-uniform diagonal-mask guard.
__global__ __launch_bounds__(256, 4) void attn_fwd(
    const u16* __restrict__ QKV, u16* __restrict__ Om)
{
    constexpr int T = 2048, LD = 3072, DO = 1024;
    constexpr int PSTR = 72;
    constexpr float NEG = -3.0e38f;

    __shared__ __align__(16) u16 Ks[2][64 * 64];     // XOR-swizzled K rows
    __shared__ __align__(16) u16 Vt[2][64 * PSTR];   // Vt[d][kv]

    const int t = threadIdx.x, lane = t & 63, w = t >> 6;
    const int ql = lane & 31, hi = lane >> 5;

    // id = slot*64 + (hd*8 + xcd): xcd = id&7 (head group, L2 locality),
    // hd = (id>>3)&7 (head within group), slot = id>>6 (q-tile, heavy first).
    const int id = (int)blockIdx.x;
    const int slot = id >> 6;
    const int bh = (id & 7) * 8 + ((id >> 3) & 7);
    const int q0 = (15 - slot) * 128;
    const int b = bh >> 4, h = bh & 15;
    const size_t rowbase = (size_t)b * T * LD + h * 64;
    const u16* Qm = QKV + rowbase;
    const u16* Km = QKV + rowbase + 1024;
    const u16* Vm = QKV + rowbase + 2048;
    const int nt = q0 / 64 + 2;                      // even (q0 % 128 == 0)

    const int qg = q0 + w * 32 + ql;
    const int qmax = q0 + w * 32 + 31;

    bf16x8 qf[4];
    {
        const u16* qp = Qm + (size_t)qg * LD + hi * 8;
        #pragma unroll
        for (int s = 0; s < 4; ++s) qf[s] = *(const bf16x8*)(qp + s * 16);
    }

    f32x16 oa[2] = {};
    float lsum = 0.f;

    // ---- staging state (pointer-increment) ----
    const int krow = t >> 3, kslot = t & 7;
    const u16* kCur = Km + (size_t)krow * LD + 8 * (kslot ^ (krow & 7));
    const int kv2 = (t & 31) * 2, dd = (t >> 5) * 8;
    const u16* vCur = Vm + (size_t)kv2 * LD + dd;
    u16x8 vva, vvb;

    auto stageK = [&](int buf) {
        u16* dst = (u16*)Ks + buf * 4096 + t * 8;
        gload_lds16(kCur, dst);
        gload_lds16(kCur + 32 * LD, dst + 2048);
        kCur += 64 * LD;
    };
    auto loadV = [&]() {
        vva = *(const u16x8*)vCur;
        vvb = *(const u16x8*)(vCur + LD);
        vCur += 64 * LD;
    };
    auto writeVt = [&](int buf) {
        u32* vd = (u32*)((u16*)Vt + buf * (64 * PSTR) + dd * PSTR + kv2);
        #pragma unroll
        for (int j = 0; j < 8; ++j)
            vd[j * (PSTR / 2)] = (u32)vva[j] | ((u32)vvb[j] << 16);
    };

    stageK(0);
    loadV();
    writeVt(0);

    for (int it0 = 0; it0 < nt; it0 += 2) {
        #pragma unroll
        for (int half = 0; half < 2; ++half) {       // fully unrolled: BUF constant
            const int BUF = half;
            const int it = it0 + half;
            const int kv0 = it * 64;
            __syncthreads();

            const bool more = (it + 1 < nt);
            if (more) { stageK(BUF ^ 1); loadV(); }

            const bool a0  = kv0 <= qmax;
            const bool a0h = kv0 + 32 <= qmax;

            // ---- S^T = K Q^T ----
            f32x16 sa[2] = {};
            __builtin_amdgcn_s_setprio(1);
            #pragma unroll
            for (int n = 0; n < 2; ++n) {
                if (!(n ? a0h : a0)) continue;
                const int row = n * 32 + ql;
                const int swz = (row & 7) << 4;
                #pragma unroll
                for (int s = 0; s < 4; ++s) {
                    bf16x8 kf = *(const bf16x8*)((const char*)Ks + BUF * 8192 + row * 128 +
                                                 ((((s << 1) | hi) << 4) ^ swz));
                    sa[n] = mfma32(kf, qf[s], sa[n]);
                }
            }
            __builtin_amdgcn_s_setprio(0);

            // ---- softmax (no-max): P = exp2(S); sum; pack (T12) ----
            u32x4 pw[2][2];
            if (a0) {
                float rs = 0.f;
                #pragma unroll
                for (int n = 0; n < 2; ++n) {
                    if (n == 1 && !a0h) continue;
                    // wave-uniform guard: any lane's max kvg (=kv0+n*32+31) vs min qg
                    if (kv0 + n * 32 + 31 > q0 + w * 32) {
                        #pragma unroll
                        for (int r = 0; r < 16; ++r) {
                            int kvg = kv0 + n * 32 + (r & 3) + 8 * (r >> 2) + 4 * hi;
                            if (kvg > qg) sa[n][r] = NEG;
                        }
                    }
                    float pv[16];
                    #pragma unroll
                    for (int r = 0; r < 16; ++r)
                        pv[r] = __builtin_exp2f(sa[n][r]);
                    float s8[8];
                    #pragma unroll
                    for (int r = 0; r < 8; ++r) s8[r] = pv[r] + pv[r + 8];
                    rs += ((s8[0] + s8[4]) + (s8[1] + s8[5])) + ((s8[2] + s8[6]) + (s8[3] + s8[7]));
                    #pragma unroll
                    for (int s = 0; s < 2; ++s) {
                        u32 u0 = cvtpk_bf16(pv[8 * s + 0], pv[8 * s + 1]);
                        u32 u1 = cvtpk_bf16(pv[8 * s + 2], pv[8 * s + 3]);
                        u32 u2 = cvtpk_bf16(pv[8 * s + 4], pv[8 * s + 5]);
                        u32 u3 = cvtpk_bf16(pv[8 * s + 6], pv[8 * s + 7]);
                        plswap(u0, u2);
                        plswap(u1, u3);
                        pw[n][s] = u32x4{u0, u1, u2, u3};
                    }
                }
                rs += __shfl_xor(rs, 32);
                lsum += rs;
            }

            // ---- O^T += V^T P^T ----
            __builtin_amdgcn_s_setprio(1);
            #pragma unroll
            for (int dt = 0; dt < 2; ++dt) {
                const int vrow = dt * 32 + ql;
                #pragma unroll
                for (int n = 0; n < 2; ++n) {
                    if (!(n ? a0h : a0)) continue;
                    #pragma unroll
                    for (int s = 0; s < 2; ++s) {
                        bf16x8 vf = *(const bf16x8*)((const u16*)Vt + BUF * (64 * PSTR) +
                                                     vrow * PSTR + n * 32 + s * 16 + hi * 8);
                        oa[dt] = mfma32(vf, __builtin_bit_cast(bf16x8, pw[n][s]), oa[dt]);
                    }
                }
            }
            __builtin_amdgcn_s_setprio(0);

            if (more) writeVt(BUF ^ 1);
        }
    }

    // ---- epilogue: transpose O^T -> O via per-wave LDS region ----
    __syncthreads();
    u16* ot = ((u16*)Vt) + w * (32 * PSTR);
    const float inv = fastrcp(lsum);
    #pragma unroll
    for (int dt = 0; dt < 2; ++dt)
        #pragma unroll
        for (int r = 0; r < 16; ++r) {
            int d = dt * 32 + (r & 3) + 8 * (r >> 2) + 4 * hi;
            ot[ql * PSTR + d] = f2bf_fast(oa[dt][r] * inv);
        }
    const int lq = lane >> 1, hv = lane & 1;
    const size_t obase = (size_t)b * T * DO + h * 64;
    const u16* src = ot + lq * PSTR + hv * 32;
    u16* dst = Om + obase + (size_t)(q0 + w * 32 + lq) * DO + hv * 32;
    #pragma unroll
    for (int seg = 0; seg < 4; ++seg)
        *(u16x8*)(dst + seg * 8) = *(const u16x8*)(src + seg * 8);
}

extern "C" void kernel_launch(void* const* d_in, const int* in_sizes, int n_in,
                              void* d_out, int out_size, void* d_ws, size_t ws_size,
                              hipStream_t stream)
{
    const float* x  = (const float*)d_in[0];
    const float* Wq = (const float*)d_in[1];
    const float* bq = (const float*)d_in[2];
    const float* Wk = (const float*)d_in[3];
    const float* bk = (const float*)d_in[4];
    const float* Wv = (const float*)d_in[5];
    const float* bv = (const float*)d_in[6];
    const float* Wo = (const float*)d_in[7];
    const float* bo = (const float*)d_in[8];

    constexpr int T = 2048, D = 1024;
    constexpr size_t MT = (size_t)4 * T;   // 8192 rows

    const size_t NEED = (size_t)74 << 20;
    if (ws_size < NEED) return;

    char* ws = (char*)d_ws;
    u16* xb    = (u16*)(ws);                          // 16 MiB (dead after QKV GEMM)
    u16* Ob    = (u16*)(ws);                          // reuses xb region
    u16* Wqkvb = (u16*)(ws + ((size_t)16 << 20));     // 6 MiB
    u16* Wob   = (u16*)(ws + ((size_t)22 << 20));     // 2 MiB
    u16* QKVb  = (u16*)(ws + ((size_t)24 << 20));     // 48 MiB
    float* bqkv = (float*)(ws + ((size_t)72 << 20));  // 12 KiB

    int nx4 = (int)(MT * D / 4);
    cvt_f32_bf16<<<(nx4 + 255) / 256, 256, 0, stream>>>(x, xb, nx4, 1.0f);
    int nw4 = D * D / 4;
    cvt_f32_bf16<<<(nw4 + 255) / 256, 256, 0, stream>>>(Wq, Wqkvb, nw4, CSCALE);
    cvt_f32_bf16<<<(nw4 + 255) / 256, 256, 0, stream>>>(Wk, Wqkvb + (size_t)D * D, nw4, 1.0f);
    cvt_f32_bf16<<<(nw4 + 255) / 256, 256, 0, stream>>>(Wv, Wqkvb + (size_t)2 * D * D, nw4, 1.0f);
    cvt_f32_bf16<<<(nw4 + 255) / 256, 256, 0, stream>>>(Wo, Wob, nw4, 1.0f);
    build_bias<<<12, 256, 0, stream>>>(bq, bk, bv, bqkv);

    // fused QKV GEMM: [8192,1024] x [3072,1024]^T -> [8192,3072]
    gemm_bt<0><<<dim3(1536), 256, 0, stream>>>(xb, Wqkvb, bqkv, QKVb, D, 3072, 3);

    attn_fwd<<<dim3(1024), 256, 0, stream>>>(QKVb, Ob);

    // output projection: [8192,1024] x [1024,1024]^T -> [8192,1024] f32
    gemm_bt<1><<<dim3(512), 256, 0, stream>>>(Ob, Wob, bo, d_out, D, 1024, 1);
}

// Round 9
// 191.991 us; speedup vs baseline: 1.2395x; 1.2395x over previous
//
#include <hip/hip_runtime.h>
#include <hip/hip_bf16.h>

#define DEV __device__ __forceinline__

typedef unsigned short u16;
typedef unsigned int u32;
typedef __attribute__((ext_vector_type(4))) float f32x4;
typedef __attribute__((ext_vector_type(16))) float f32x16;
typedef __attribute__((ext_vector_type(8))) __bf16 bf16x8;
typedef __attribute__((ext_vector_type(8))) u16 u16x8;
typedef __attribute__((ext_vector_type(4))) u16 u16x4;
typedef __attribute__((ext_vector_type(4))) u32 u32x4;

// 0.125 * log2(e): folded into Wq/bq so S comes out of QK^T pre-scaled for exp2
#define CSCALE 0.18033688011112042f

DEV u16 f2bf(float f) {
    u32 u = __builtin_bit_cast(u32, f);
    u32 r = (u + 0x7fffu + ((u >> 16) & 1u)) >> 16;
    return (u16)r;
}

DEV u16 f2bf_fast(float f) {
    u32 u = __builtin_bit_cast(u32, f);
    return (u16)((u + 0x8000u) >> 16);
}

DEV float fastrcp(float x) {
#if __has_builtin(__builtin_amdgcn_rcpf)
    return __builtin_amdgcn_rcpf(x);
#else
    return 1.0f / x;
#endif
}

DEV u32 cvtpk_bf16(float lo, float hi) {
    u32 r;
    asm("v_cvt_pk_bf16_f32 %0, %1, %2" : "=v"(r) : "v"(lo), "v"(hi));
    return r;
}

DEV void plswap(u32& a, u32& b) {
    asm volatile("v_permlane32_swap_b32 %0, %1" : "+v"(a), "+v"(b));
}

DEV void gload_lds16(const void* g, void* l) {
    void* gg = const_cast<void*>(g);
    __builtin_amdgcn_global_load_lds(
        (const __attribute__((address_space(1))) void*)gg,
        (__attribute__((address_space(3))) void*)l,
        16, 0, 0);
}

DEV f32x16 mfma32(bf16x8 a, bf16x8 b, f32x16 c) {
    return __builtin_amdgcn_mfma_f32_32x32x16_bf16(a, b, c, 0, 0, 0);
}

// ---------------- f32 -> bf16 conversion (optional scale) ----------------
__global__ void cvt_f32_bf16(const float* __restrict__ in, u16* __restrict__ out,
                             int n4, float scale) {
    int i = blockIdx.x * blockDim.x + threadIdx.x;
    if (i < n4) {
        float4 v = ((const float4*)in)[i];
        u16x4 o;
        o[0] = f2bf(v.x * scale); o[1] = f2bf(v.y * scale);
        o[2] = f2bf(v.z * scale); o[3] = f2bf(v.w * scale);
        ((u16x4*)out)[i] = o;
    }
}

// ---------------- concat bias [bq*C | bk | bv] -> f32[3072] ----------------
__global__ void build_bias(const float* __restrict__ bq, const float* __restrict__ bk,
                           const float* __restrict__ bv, float* __restrict__ o) {
    int i = blockIdx.x * blockDim.x + threadIdx.x;
    if (i < 3072) {
        float v;
        if (i < 1024) v = bq[i] * CSCALE;
        else if (i < 2048) v = bk[i - 1024];
        else v = bv[i - 2048];
        o[i] = v;
    }
}

// ---------------- GEMM: C[M,N] = A[M,K] * B[N,K]^T + bias ----------------
// 1D grid, XCD-chunked swizzle: xcd = id&7 owns bn columns [xcd*bnPerXcd, ...).
template<int F32OUT>
__global__ __launch_bounds__(256) void gemm_bt(
    const u16* __restrict__ A, const u16* __restrict__ B,
    const float* __restrict__ bias, void* __restrict__ Cv,
    int K, int ldc, int bnPerXcd)
{
    __shared__ u16 As[128 * 64];
    __shared__ u16 Bs[128 * 64];
    const int t = threadIdx.x;
    const int lane = t & 63;
    const int w = t >> 6;
    const int wm = w >> 1, wn = w & 1;
    const int id = (int)blockIdx.x;
    const int xcd = id & 7, r = id >> 3;
    const int bm = (r & 63) * 128;
    const int bn = (xcd * bnPerXcd + (r >> 6)) * 128;
    const int lr = lane & 15;
    const int lg = lane >> 4;

    f32x4 acc[4][4] = {};

    for (int k0 = 0; k0 < K; k0 += 64) {
        #pragma unroll
        for (int i = 0; i < 4; ++i) {
            int off = (t + i * 256) * 16;
            int row = off >> 7;
            int colb = off & 127;
            gload_lds16((const char*)A + ((size_t)(bm + row) * K + k0) * 2 + colb,
                        (char*)As + off);
            gload_lds16((const char*)B + ((size_t)(bn + row) * K + k0) * 2 + colb,
                        (char*)Bs + off);
        }
        __syncthreads();
        #pragma unroll
        for (int kk = 0; kk < 2; ++kk) {
            bf16x8 af[4], bfr[4];
            #pragma unroll
            for (int m = 0; m < 4; ++m)
                af[m] = *(const bf16x8*)&As[(wm * 64 + m * 16 + lr) * 64 + kk * 32 + lg * 8];
            #pragma unroll
            for (int n = 0; n < 4; ++n)
                bfr[n] = *(const bf16x8*)&Bs[(wn * 64 + n * 16 + lr) * 64 + kk * 32 + lg * 8];
            #pragma unroll
            for (int m = 0; m < 4; ++m)
                #pragma unroll
                for (int n = 0; n < 4; ++n)
                    acc[m][n] = __builtin_amdgcn_mfma_f32_16x16x32_bf16(af[m], bfr[n], acc[m][n], 0, 0, 0);
        }
        __syncthreads();
    }

    #pragma unroll
    for (int n = 0; n < 4; ++n) {
        int col = bn + wn * 64 + n * 16 + lr;
        float bv = bias[col];
        #pragma unroll
        for (int m = 0; m < 4; ++m) {
            int row0 = bm + wm * 64 + m * 16 + lg * 4;
            #pragma unroll
            for (int r2 = 0; r2 < 4; ++r2) {
                float v = acc[m][n][r2] + bv;
                size_t idx = (size_t)(row0 + r2) * ldc + col;
                if (F32OUT) ((float*)Cv)[idx] = v;
                else        ((u16*)Cv)[idx] = f2bf(v);
            }
        }
    }
}

// ---------------- causal flash attention, v9 ----------------
// = v8 structure (single 128-row q-tile per block, 1024 blocks, heavy-first,
// XCD head-grouping) but WITHOUT the v8 register cap: __launch_bounds__(256,2)
// lets the allocator use ~100-128 VGPR (no spill); 4 blocks/CU fit by VGPR+LDS.
__global__ __launch_bounds__(256, 2) void attn_fwd(
    const u16* __restrict__ QKV, u16* __restrict__ Om)
{
    constexpr int T = 2048, LD = 3072, DO = 1024;
    constexpr int PSTR = 72;
    constexpr float NEG = -3.0e38f;

    __shared__ __align__(16) u16 Ks[2][64 * 64];     // XOR-swizzled K rows
    __shared__ __align__(16) u16 Vt[2][64 * PSTR];   // Vt[d][kv]

    const int t = threadIdx.x, lane = t & 63, w = t >> 6;
    const int ql = lane & 31, hi = lane >> 5;

    // id = slot*64 + (hd*8 + xcd): xcd = id&7 (head group, L2 locality),
    // hd = (id>>3)&7 (head within group), slot = id>>6 (q-tile, heavy first).
    const int id = (int)blockIdx.x;
    const int slot = id >> 6;
    const int bh = (id & 7) * 8 + ((id >> 3) & 7);
    const int q0 = (15 - slot) * 128;
    const int b = bh >> 4, h = bh & 15;
    const size_t rowbase = (size_t)b * T * LD + h * 64;
    const u16* Qm = QKV + rowbase;
    const u16* Km = QKV + rowbase + 1024;
    const u16* Vm = QKV + rowbase + 2048;
    const int nt = q0 / 64 + 2;                      // even (q0 % 128 == 0)

    const int qg = q0 + w * 32 + ql;
    const int qmax = q0 + w * 32 + 31;

    bf16x8 qf[4];
    {
        const u16* qp = Qm + (size_t)qg * LD + hi * 8;
        #pragma unroll
        for (int s = 0; s < 4; ++s) qf[s] = *(const bf16x8*)(qp + s * 16);
    }

    f32x16 oa[2] = {};
    float lsum = 0.f;

    // ---- staging state (pointer-increment) ----
    const int krow = t >> 3, kslot = t & 7;
    const u16* kCur = Km + (size_t)krow * LD + 8 * (kslot ^ (krow & 7));
    const int kv2 = (t & 31) * 2, dd = (t >> 5) * 8;
    const u16* vCur = Vm + (size_t)kv2 * LD + dd;
    u16x8 vva, vvb;

    auto stageK = [&](int buf) {
        u16* dst = (u16*)Ks + buf * 4096 + t * 8;
        gload_lds16(kCur, dst);
        gload_lds16(kCur + 32 * LD, dst + 2048);
        kCur += 64 * LD;
    };
    auto loadV = [&]() {
        vva = *(const u16x8*)vCur;
        vvb = *(const u16x8*)(vCur + LD);
        vCur += 64 * LD;
    };
    auto writeVt = [&](int buf) {
        u32* vd = (u32*)((u16*)Vt + buf * (64 * PSTR) + dd * PSTR + kv2);
        #pragma unroll
        for (int j = 0; j < 8; ++j)
            vd[j * (PSTR / 2)] = (u32)vva[j] | ((u32)vvb[j] << 16);
    };

    stageK(0);
    loadV();
    writeVt(0);

    for (int it0 = 0; it0 < nt; it0 += 2) {
        #pragma unroll
        for (int half = 0; half < 2; ++half) {       // fully unrolled: BUF constant
            const int BUF = half;
            const int it = it0 + half;
            const int kv0 = it * 64;
            __syncthreads();

            const bool more = (it + 1 < nt);
            if (more) { stageK(BUF ^ 1); loadV(); }

            const bool a0  = kv0 <= qmax;
            const bool a0h = kv0 + 32 <= qmax;

            // ---- S^T = K Q^T ----
            f32x16 sa[2] = {};
            __builtin_amdgcn_s_setprio(1);
            #pragma unroll
            for (int n = 0; n < 2; ++n) {
                if (!(n ? a0h : a0)) continue;
                const int row = n * 32 + ql;
                const int swz = (row & 7) << 4;
                #pragma unroll
                for (int s = 0; s < 4; ++s) {
                    bf16x8 kf = *(const bf16x8*)((const char*)Ks + BUF * 8192 + row * 128 +
                                                 ((((s << 1) | hi) << 4) ^ swz));
                    sa[n] = mfma32(kf, qf[s], sa[n]);
                }
            }
            __builtin_amdgcn_s_setprio(0);

            // ---- softmax (no-max): P = exp2(S); sum; pack (T12) ----
            u32x4 pw[2][2];
            if (a0) {
                float rs = 0.f;
                #pragma unroll
                for (int n = 0; n < 2; ++n) {
                    if (n == 1 && !a0h) continue;
                    // wave-uniform guard: any lane's max kvg (=kv0+n*32+31) vs min qg
                    if (kv0 + n * 32 + 31 > q0 + w * 32) {
                        #pragma unroll
                        for (int r = 0; r < 16; ++r) {
                            int kvg = kv0 + n * 32 + (r & 3) + 8 * (r >> 2) + 4 * hi;
                            if (kvg > qg) sa[n][r] = NEG;
                        }
                    }
                    float pv[16];
                    #pragma unroll
                    for (int r = 0; r < 16; ++r)
                        pv[r] = __builtin_exp2f(sa[n][r]);
                    float s8[8];
                    #pragma unroll
                    for (int r = 0; r < 8; ++r) s8[r] = pv[r] + pv[r + 8];
                    rs += ((s8[0] + s8[4]) + (s8[1] + s8[5])) + ((s8[2] + s8[6]) + (s8[3] + s8[7]));
                    #pragma unroll
                    for (int s = 0; s < 2; ++s) {
                        u32 u0 = cvtpk_bf16(pv[8 * s + 0], pv[8 * s + 1]);
                        u32 u1 = cvtpk_bf16(pv[8 * s + 2], pv[8 * s + 3]);
                        u32 u2 = cvtpk_bf16(pv[8 * s + 4], pv[8 * s + 5]);
                        u32 u3 = cvtpk_bf16(pv[8 * s + 6], pv[8 * s + 7]);
                        plswap(u0, u2);
                        plswap(u1, u3);
                        pw[n][s] = u32x4{u0, u1, u2, u3};
                    }
                }
                rs += __shfl_xor(rs, 32);
                lsum += rs;
            }

            // ---- O^T += V^T P^T ----
            __builtin_amdgcn_s_setprio(1);
            #pragma unroll
            for (int dt = 0; dt < 2; ++dt) {
                const int vrow = dt * 32 + ql;
                #pragma unroll
                for (int n = 0; n < 2; ++n) {
                    if (!(n ? a0h : a0)) continue;
                    #pragma unroll
                    for (int s = 0; s < 2; ++s) {
                        bf16x8 vf = *(const bf16x8*)((const u16*)Vt + BUF * (64 * PSTR) +
                                                     vrow * PSTR + n * 32 + s * 16 + hi * 8);
                        oa[dt] = mfma32(vf, __builtin_bit_cast(bf16x8, pw[n][s]), oa[dt]);
                    }
                }
            }
            __builtin_amdgcn_s_setprio(0);

            if (more) writeVt(BUF ^ 1);
        }
    }

    // ---- epilogue: transpose O^T -> O via per-wave LDS region ----
    __syncthreads();
    u16* ot = ((u16*)Vt) + w * (32 * PSTR);
    const float inv = fastrcp(lsum);
    #pragma unroll
    for (int dt = 0; dt < 2; ++dt)
        #pragma unroll
        for (int r = 0; r < 16; ++r) {
            int d = dt * 32 + (r & 3) + 8 * (r >> 2) + 4 * hi;
            ot[ql * PSTR + d] = f2bf_fast(oa[dt][r] * inv);
        }
    const int lq = lane >> 1, hv = lane & 1;
    const size_t obase = (size_t)b * T * DO + h * 64;
    const u16* src = ot + lq * PSTR + hv * 32;
    u16* dst = Om + obase + (size_t)(q0 + w * 32 + lq) * DO + hv * 32;
    #pragma unroll
    for (int seg = 0; seg < 4; ++seg)
        *(u16x8*)(dst + seg * 8) = *(const u16x8*)(src + seg * 8);
}

extern "C" void kernel_launch(void* const* d_in, const int* in_sizes, int n_in,
                              void* d_out, int out_size, void* d_ws, size_t ws_size,
                              hipStream_t stream)
{
    const float* x  = (const float*)d_in[0];
    const float* Wq = (const float*)d_in[1];
    const float* bq = (const float*)d_in[2];
    const float* Wk = (const float*)d_in[3];
    const float* bk = (const float*)d_in[4];
    const float* Wv = (const float*)d_in[5];
    const float* bv = (const float*)d_in[6];
    const float* Wo = (const float*)d_in[7];
    const float* bo = (const float*)d_in[8];

    constexpr int T = 2048, D = 1024;
    constexpr size_t MT = (size_t)4 * T;   // 8192 rows

    const size_t NEED = (size_t)74 << 20;
    if (ws_size < NEED) return;

    char* ws = (char*)d_ws;
    u16* xb    = (u16*)(ws);                          // 16 MiB (dead after QKV GEMM)
    u16* Ob    = (u16*)(ws);                          // reuses xb region
    u16* Wqkvb = (u16*)(ws + ((size_t)16 << 20));     // 6 MiB
    u16* Wob   = (u16*)(ws + ((size_t)22 << 20));     // 2 MiB
    u16* QKVb  = (u16*)(ws + ((size_t)24 << 20));     // 48 MiB
    float* bqkv = (float*)(ws + ((size_t)72 << 20));  // 12 KiB

    int nx4 = (int)(MT * D / 4);
    cvt_f32_bf16<<<(nx4 + 255) / 256, 256, 0, stream>>>(x, xb, nx4, 1.0f);
    int nw4 = D * D / 4;
    cvt_f32_bf16<<<(nw4 + 255) / 256, 256, 0, stream>>>(Wq, Wqkvb, nw4, CSCALE);
    cvt_f32_bf16<<<(nw4 + 255) / 256, 256, 0, stream>>>(Wk, Wqkvb + (size_t)D * D, nw4, 1.0f);
    cvt_f32_bf16<<<(nw4 + 255) / 256, 256, 0, stream>>>(Wv, Wqkvb + (size_t)2 * D * D, nw4, 1.0f);
    cvt_f32_bf16<<<(nw4 + 255) / 256, 256, 0, stream>>>(Wo, Wob, nw4, 1.0f);
    build_bias<<<12, 256, 0, stream>>>(bq, bk, bv, bqkv);

    // fused QKV GEMM: [8192,1024] x [3072,1024]^T -> [8192,3072]
    gemm_bt<0><<<dim3(1536), 256, 0, stream>>>(xb, Wqkvb, bqkv, QKVb, D, 3072, 3);

    attn_fwd<<<dim3(1024), 256, 0, stream>>>(QKVb, Ob);

    // output projection: [8192,1024] x [1024,1024]^T -> [8192,1024] f32
    gemm_bt<1><<<dim3(512), 256, 0, stream>>>(Ob, Wob, bo, d_out, D, 1024, 1);
}

// Round 10
// 189.245 us; speedup vs baseline: 1.2575x; 1.0145x over previous
//
#include <hip/hip_runtime.h>
#include <hip/hip_bf16.h>

#define DEV __device__ __forceinline__

typedef unsigned short u16;
typedef unsigned int u32;
typedef __attribute__((ext_vector_type(4))) float f32x4;
typedef __attribute__((ext_vector_type(16))) float f32x16;
typedef __attribute__((ext_vector_type(8))) __bf16 bf16x8;
typedef __attribute__((ext_vector_type(8))) u16 u16x8;
typedef __attribute__((ext_vector_type(4))) u16 u16x4;
typedef __attribute__((ext_vector_type(4))) u32 u32x4;

// 0.125 * log2(e): folded into Wq/bq so S comes out of QK^T pre-scaled for exp2
#define CSCALE 0.18033688011112042f

DEV u16 f2bf(float f) {
    u32 u = __builtin_bit_cast(u32, f);
    u32 r = (u + 0x7fffu + ((u >> 16) & 1u)) >> 16;
    return (u16)r;
}

DEV u16 f2bf_fast(float f) {
    u32 u = __builtin_bit_cast(u32, f);
    return (u16)((u + 0x8000u) >> 16);
}

DEV float fastrcp(float x) {
#if __has_builtin(__builtin_amdgcn_rcpf)
    return __builtin_amdgcn_rcpf(x);
#else
    return 1.0f / x;
#endif
}

DEV u32 cvtpk_bf16(float lo, float hi) {
    u32 r;
    asm("v_cvt_pk_bf16_f32 %0, %1, %2" : "=v"(r) : "v"(lo), "v"(hi));
    return r;
}

DEV void plswap(u32& a, u32& b) {
    asm volatile("v_permlane32_swap_b32 %0, %1" : "+v"(a), "+v"(b));
}

DEV void gload_lds16(const void* g, void* l) {
    void* gg = const_cast<void*>(g);
    __builtin_amdgcn_global_load_lds(
        (const __attribute__((address_space(1))) void*)gg,
        (__attribute__((address_space(3))) void*)l,
        16, 0, 0);
}

DEV f32x16 mfma32(bf16x8 a, bf16x8 b, f32x16 c) {
    return __builtin_amdgcn_mfma_f32_32x32x16_bf16(a, b, c, 0, 0, 0);
}

// ---------------- f32 -> bf16 conversion (optional scale) ----------------
__global__ void cvt_f32_bf16(const float* __restrict__ in, u16* __restrict__ out,
                             int n4, float scale) {
    int i = blockIdx.x * blockDim.x + threadIdx.x;
    if (i < n4) {
        float4 v = ((const float4*)in)[i];
        u16x4 o;
        o[0] = f2bf(v.x * scale); o[1] = f2bf(v.y * scale);
        o[2] = f2bf(v.z * scale); o[3] = f2bf(v.w * scale);
        ((u16x4*)out)[i] = o;
    }
}

// ---------------- concat bias [bq*C | bk | bv] -> f32[3072] ----------------
__global__ void build_bias(const float* __restrict__ bq, const float* __restrict__ bk,
                           const float* __restrict__ bv, float* __restrict__ o) {
    int i = blockIdx.x * blockDim.x + threadIdx.x;
    if (i < 3072) {
        float v;
        if (i < 1024) v = bq[i] * CSCALE;
        else if (i < 2048) v = bk[i - 1024];
        else v = bv[i - 2048];
        o[i] = v;
    }
}

// ---------------- GEMM: C[M,N] = A[M,K] * B[N,K]^T + bias ----------------
// 1D grid. XCD-aware, COLUMN-FAST traversal: xcd = id&7 owns bn columns
// [xcd*bnPerXcd, (xcd+1)*bnPerXcd); within an XCD consecutive blocks cycle
// columns (A row-panel L2-reused), row-groups advance in lockstep across
// XCDs (A panel HBM-fetched once, L3-served to the other 7).
template<int F32OUT>
__global__ __launch_bounds__(256) void gemm_bt(
    const u16* __restrict__ A, const u16* __restrict__ B,
    const float* __restrict__ bias, void* __restrict__ Cv,
    int K, int ldc, int bnPerXcd)
{
    __shared__ u16 As[128 * 64];
    __shared__ u16 Bs[128 * 64];
    const int t = threadIdx.x;
    const int lane = t & 63;
    const int w = t >> 6;
    const int wm = w >> 1, wn = w & 1;
    const int id = (int)blockIdx.x;
    const int xcd = id & 7, r = id >> 3;
    const int bm = (r / bnPerXcd) * 128;
    const int bn = (xcd * bnPerXcd + r % bnPerXcd) * 128;
    const int lr = lane & 15;
    const int lg = lane >> 4;

    f32x4 acc[4][4] = {};

    for (int k0 = 0; k0 < K; k0 += 64) {
        #pragma unroll
        for (int i = 0; i < 4; ++i) {
            int off = (t + i * 256) * 16;
            int row = off >> 7;
            int colb = off & 127;
            gload_lds16((const char*)A + ((size_t)(bm + row) * K + k0) * 2 + colb,
                        (char*)As + off);
            gload_lds16((const char*)B + ((size_t)(bn + row) * K + k0) * 2 + colb,
                        (char*)Bs + off);
        }
        __syncthreads();
        #pragma unroll
        for (int kk = 0; kk < 2; ++kk) {
            bf16x8 af[4], bfr[4];
            #pragma unroll
            for (int m = 0; m < 4; ++m)
                af[m] = *(const bf16x8*)&As[(wm * 64 + m * 16 + lr) * 64 + kk * 32 + lg * 8];
            #pragma unroll
            for (int n = 0; n < 4; ++n)
                bfr[n] = *(const bf16x8*)&Bs[(wn * 64 + n * 16 + lr) * 64 + kk * 32 + lg * 8];
            #pragma unroll
            for (int m = 0; m < 4; ++m)
                #pragma unroll
                for (int n = 0; n < 4; ++n)
                    acc[m][n] = __builtin_amdgcn_mfma_f32_16x16x32_bf16(af[m], bfr[n], acc[m][n], 0, 0, 0);
        }
        __syncthreads();
    }

    #pragma unroll
    for (int n = 0; n < 4; ++n) {
        int col = bn + wn * 64 + n * 16 + lr;
        float bv = bias[col];
        #pragma unroll
        for (int m = 0; m < 4; ++m) {
            int row0 = bm + wm * 64 + m * 16 + lg * 4;
            #pragma unroll
            for (int r2 = 0; r2 < 4; ++r2) {
                float v = acc[m][n][r2] + bv;
                size_t idx = (size_t)(row0 + r2) * ldc + col;
                if (F32OUT) ((float*)Cv)[idx] = v;
                else        ((u16*)Cv)[idx] = f2bf(v);
            }
        }
    }
}

// ---------------- causal flash attention, v9 (unchanged from R9) ----------
__global__ __launch_bounds__(256, 2) void attn_fwd(
    const u16* __restrict__ QKV, u16* __restrict__ Om)
{
    constexpr int T = 2048, LD = 3072, DO = 1024;
    constexpr int PSTR = 72;
    constexpr float NEG = -3.0e38f;

    __shared__ __align__(16) u16 Ks[2][64 * 64];     // XOR-swizzled K rows
    __shared__ __align__(16) u16 Vt[2][64 * PSTR];   // Vt[d][kv]

    const int t = threadIdx.x, lane = t & 63, w = t >> 6;
    const int ql = lane & 31, hi = lane >> 5;

    const int id = (int)blockIdx.x;
    const int slot = id >> 6;
    const int bh = (id & 7) * 8 + ((id >> 3) & 7);
    const int q0 = (15 - slot) * 128;
    const int b = bh >> 4, h = bh & 15;
    const size_t rowbase = (size_t)b * T * LD + h * 64;
    const u16* Qm = QKV + rowbase;
    const u16* Km = QKV + rowbase + 1024;
    const u16* Vm = QKV + rowbase + 2048;
    const int nt = q0 / 64 + 2;                      // even (q0 % 128 == 0)

    const int qg = q0 + w * 32 + ql;
    const int qmax = q0 + w * 32 + 31;

    bf16x8 qf[4];
    {
        const u16* qp = Qm + (size_t)qg * LD + hi * 8;
        #pragma unroll
        for (int s = 0; s < 4; ++s) qf[s] = *(const bf16x8*)(qp + s * 16);
    }

    f32x16 oa[2] = {};
    float lsum = 0.f;

    const int krow = t >> 3, kslot = t & 7;
    const u16* kCur = Km + (size_t)krow * LD + 8 * (kslot ^ (krow & 7));
    const int kv2 = (t & 31) * 2, dd = (t >> 5) * 8;
    const u16* vCur = Vm + (size_t)kv2 * LD + dd;
    u16x8 vva, vvb;

    auto stageK = [&](int buf) {
        u16* dst = (u16*)Ks + buf * 4096 + t * 8;
        gload_lds16(kCur, dst);
        gload_lds16(kCur + 32 * LD, dst + 2048);
        kCur += 64 * LD;
    };
    auto loadV = [&]() {
        vva = *(const u16x8*)vCur;
        vvb = *(const u16x8*)(vCur + LD);
        vCur += 64 * LD;
    };
    auto writeVt = [&](int buf) {
        u32* vd = (u32*)((u16*)Vt + buf * (64 * PSTR) + dd * PSTR + kv2);
        #pragma unroll
        for (int j = 0; j < 8; ++j)
            vd[j * (PSTR / 2)] = (u32)vva[j] | ((u32)vvb[j] << 16);
    };

    stageK(0);
    loadV();
    writeVt(0);

    for (int it0 = 0; it0 < nt; it0 += 2) {
        #pragma unroll
        for (int half = 0; half < 2; ++half) {       // fully unrolled: BUF constant
            const int BUF = half;
            const int it = it0 + half;
            const int kv0 = it * 64;
            __syncthreads();

            const bool more = (it + 1 < nt);
            if (more) { stageK(BUF ^ 1); loadV(); }

            const bool a0  = kv0 <= qmax;
            const bool a0h = kv0 + 32 <= qmax;

            // ---- S^T = K Q^T ----
            f32x16 sa[2] = {};
            __builtin_amdgcn_s_setprio(1);
            #pragma unroll
            for (int n = 0; n < 2; ++n) {
                if (!(n ? a0h : a0)) continue;
                const int row = n * 32 + ql;
                const int swz = (row & 7) << 4;
                #pragma unroll
                for (int s = 0; s < 4; ++s) {
                    bf16x8 kf = *(const bf16x8*)((const char*)Ks + BUF * 8192 + row * 128 +
                                                 ((((s << 1) | hi) << 4) ^ swz));
                    sa[n] = mfma32(kf, qf[s], sa[n]);
                }
            }
            __builtin_amdgcn_s_setprio(0);

            // ---- softmax (no-max): P = exp2(S); sum; pack (T12) ----
            u32x4 pw[2][2];
            if (a0) {
                float rs = 0.f;
                #pragma unroll
                for (int n = 0; n < 2; ++n) {
                    if (n == 1 && !a0h) continue;
                    if (kv0 + n * 32 + 31 > q0 + w * 32) {
                        #pragma unroll
                        for (int r = 0; r < 16; ++r) {
                            int kvg = kv0 + n * 32 + (r & 3) + 8 * (r >> 2) + 4 * hi;
                            if (kvg > qg) sa[n][r] = NEG;
                        }
                    }
                    float pv[16];
                    #pragma unroll
                    for (int r = 0; r < 16; ++r)
                        pv[r] = __builtin_exp2f(sa[n][r]);
                    float s8[8];
                    #pragma unroll
                    for (int r = 0; r < 8; ++r) s8[r] = pv[r] + pv[r + 8];
                    rs += ((s8[0] + s8[4]) + (s8[1] + s8[5])) + ((s8[2] + s8[6]) + (s8[3] + s8[7]));
                    #pragma unroll
                    for (int s = 0; s < 2; ++s) {
                        u32 u0 = cvtpk_bf16(pv[8 * s + 0], pv[8 * s + 1]);
                        u32 u1 = cvtpk_bf16(pv[8 * s + 2], pv[8 * s + 3]);
                        u32 u2 = cvtpk_bf16(pv[8 * s + 4], pv[8 * s + 5]);
                        u32 u3 = cvtpk_bf16(pv[8 * s + 6], pv[8 * s + 7]);
                        plswap(u0, u2);
                        plswap(u1, u3);
                        pw[n][s] = u32x4{u0, u1, u2, u3};
                    }
                }
                rs += __shfl_xor(rs, 32);
                lsum += rs;
            }

            // ---- O^T += V^T P^T ----
            __builtin_amdgcn_s_setprio(1);
            #pragma unroll
            for (int dt = 0; dt < 2; ++dt) {
                const int vrow = dt * 32 + ql;
                #pragma unroll
                for (int n = 0; n < 2; ++n) {
                    if (!(n ? a0h : a0)) continue;
                    #pragma unroll
                    for (int s = 0; s < 2; ++s) {
                        bf16x8 vf = *(const bf16x8*)((const u16*)Vt + BUF * (64 * PSTR) +
                                                     vrow * PSTR + n * 32 + s * 16 + hi * 8);
                        oa[dt] = mfma32(vf, __builtin_bit_cast(bf16x8, pw[n][s]), oa[dt]);
                    }
                }
            }
            __builtin_amdgcn_s_setprio(0);

            if (more) writeVt(BUF ^ 1);
        }
    }

    // ---- epilogue: transpose O^T -> O via per-wave LDS region ----
    __syncthreads();
    u16* ot = ((u16*)Vt) + w * (32 * PSTR);
    const float inv = fastrcp(lsum);
    #pragma unroll
    for (int dt = 0; dt < 2; ++dt)
        #pragma unroll
        for (int r = 0; r < 16; ++r) {
            int d = dt * 32 + (r & 3) + 8 * (r >> 2) + 4 * hi;
            ot[ql * PSTR + d] = f2bf_fast(oa[dt][r] * inv);
        }
    const int lq = lane >> 1, hv = lane & 1;
    const size_t obase = (size_t)b * T * DO + h * 64;
    const u16* src = ot + lq * PSTR + hv * 32;
    u16* dst = Om + obase + (size_t)(q0 + w * 32 + lq) * DO + hv * 32;
    #pragma unroll
    for (int seg = 0; seg < 4; ++seg)
        *(u16x8*)(dst + seg * 8) = *(const u16x8*)(src + seg * 8);
}

extern "C" void kernel_launch(void* const* d_in, const int* in_sizes, int n_in,
                              void* d_out, int out_size, void* d_ws, size_t ws_size,
                              hipStream_t stream)
{
    const float* x  = (const float*)d_in[0];
    const float* Wq = (const float*)d_in[1];
    const float* bq = (const float*)d_in[2];
    const float* Wk = (const float*)d_in[3];
    const float* bk = (const float*)d_in[4];
    const float* Wv = (const float*)d_in[5];
    const float* bv = (const float*)d_in[6];
    const float* Wo = (const float*)d_in[7];
    const float* bo = (const float*)d_in[8];

    constexpr int T = 2048, D = 1024;
    constexpr size_t MT = (size_t)4 * T;   // 8192 rows

    const size_t NEED = (size_t)74 << 20;
    if (ws_size < NEED) return;

    char* ws = (char*)d_ws;
    u16* xb    = (u16*)(ws);                          // 16 MiB (dead after QKV GEMM)
    u16* Ob    = (u16*)(ws);                          // reuses xb region
    u16* Wqkvb = (u16*)(ws + ((size_t)16 << 20));     // 6 MiB
    u16* Wob   = (u16*)(ws + ((size_t)22 << 20));     // 2 MiB
    u16* QKVb  = (u16*)(ws + ((size_t)24 << 20));     // 48 MiB
    float* bqkv = (float*)(ws + ((size_t)72 << 20));  // 12 KiB

    int nx4 = (int)(MT * D / 4);
    cvt_f32_bf16<<<(nx4 + 255) / 256, 256, 0, stream>>>(x, xb, nx4, 1.0f);
    int nw4 = D * D / 4;
    cvt_f32_bf16<<<(nw4 + 255) / 256, 256, 0, stream>>>(Wq, Wqkvb, nw4, CSCALE);
    cvt_f32_bf16<<<(nw4 + 255) / 256, 256, 0, stream>>>(Wk, Wqkvb + (size_t)D * D, nw4, 1.0f);
    cvt_f32_bf16<<<(nw4 + 255) / 256, 256, 0, stream>>>(Wv, Wqkvb + (size_t)2 * D * D, nw4, 1.0f);
    cvt_f32_bf16<<<(nw4 + 255) / 256, 256, 0, stream>>>(Wo, Wob, nw4, 1.0f);
    build_bias<<<12, 256, 0, stream>>>(bq, bk, bv, bqkv);

    // fused QKV GEMM: [8192,1024] x [3072,1024]^T -> [8192,3072]
    gemm_bt<0><<<dim3(1536), 256, 0, stream>>>(xb, Wqkvb, bqkv, QKVb, D, 3072, 3);

    attn_fwd<<<dim3(1024), 256, 0, stream>>>(QKVb, Ob);

    // output projection: [8192,1024] x [1024,1024]^T -> [8192,1024] f32
    gemm_bt<1><<<dim3(512), 256, 0, stream>>>(Ob, Wob, bo, d_out, D, 1024, 1);
}

// Round 11
// 175.692 us; speedup vs baseline: 1.3545x; 1.0771x over previous
//
#include <hip/hip_runtime.h>
#include <hip/hip_bf16.h>

#define DEV __device__ __forceinline__

typedef unsigned short u16;
typedef unsigned int u32;
typedef __attribute__((ext_vector_type(4))) float f32x4;
typedef __attribute__((ext_vector_type(16))) float f32x16;
typedef __attribute__((ext_vector_type(8))) __bf16 bf16x8;
typedef __attribute__((ext_vector_type(8))) u16 u16x8;
typedef __attribute__((ext_vector_type(4))) u16 u16x4;
typedef __attribute__((ext_vector_type(4))) u32 u32x4;

// 0.125 * log2(e): folded into Wq/bq so S comes out of QK^T pre-scaled for exp2
#define CSCALE 0.18033688011112042f

DEV u16 f2bf(float f) {
    u32 u = __builtin_bit_cast(u32, f);
    u32 r = (u + 0x7fffu + ((u >> 16) & 1u)) >> 16;
    return (u16)r;
}

DEV u16 f2bf_fast(float f) {
    u32 u = __builtin_bit_cast(u32, f);
    return (u16)((u + 0x8000u) >> 16);
}

DEV float fastrcp(float x) {
#if __has_builtin(__builtin_amdgcn_rcpf)
    return __builtin_amdgcn_rcpf(x);
#else
    return 1.0f / x;
#endif
}

DEV u32 cvtpk_bf16(float lo, float hi) {
    u32 r;
    asm("v_cvt_pk_bf16_f32 %0, %1, %2" : "=v"(r) : "v"(lo), "v"(hi));
    return r;
}

DEV void plswap(u32& a, u32& b) {
    asm volatile("v_permlane32_swap_b32 %0, %1" : "+v"(a), "+v"(b));
}

DEV void gload_lds16(const void* g, void* l) {
    void* gg = const_cast<void*>(g);
    __builtin_amdgcn_global_load_lds(
        (const __attribute__((address_space(1))) void*)gg,
        (__attribute__((address_space(3))) void*)l,
        16, 0, 0);
}

DEV f32x16 mfma32(bf16x8 a, bf16x8 b, f32x16 c) {
    return __builtin_amdgcn_mfma_f32_32x32x16_bf16(a, b, c, 0, 0, 0);
}

// ---------------- f32 -> bf16 conversion (optional scale) ----------------
__global__ void cvt_f32_bf16(const float* __restrict__ in, u16* __restrict__ out,
                             int n4, float scale) {
    int i = blockIdx.x * blockDim.x + threadIdx.x;
    if (i < n4) {
        float4 v = ((const float4*)in)[i];
        u16x4 o;
        o[0] = f2bf(v.x * scale); o[1] = f2bf(v.y * scale);
        o[2] = f2bf(v.z * scale); o[3] = f2bf(v.w * scale);
        ((u16x4*)out)[i] = o;
    }
}

// ---------------- concat bias [bq*C | bk | bv] -> f32[3072] ----------------
__global__ void build_bias(const float* __restrict__ bq, const float* __restrict__ bk,
                           const float* __restrict__ bv, float* __restrict__ o) {
    int i = blockIdx.x * blockDim.x + threadIdx.x;
    if (i < 3072) {
        float v;
        if (i < 1024) v = bq[i] * CSCALE;
        else if (i < 2048) v = bk[i - 1024];
        else v = bv[i - 2048];
        o[i] = v;
    }
}

// ---------------- GEMM: C[M,N] = A[M,K] * B[N,K]^T + bias ----------------
// Column-fast XCD traversal (R10) + T2 granule-XOR LDS swizzle (R11):
// LDS granule (row, g) holds global granule g^(row&7); fragment reads XOR the
// byte offset with ((lr&7)<<4) -> 16-way bank conflict becomes 2-way (free).
template<int F32OUT>
__global__ __launch_bounds__(256) void gemm_bt(
    const u16* __restrict__ A, const u16* __restrict__ B,
    const float* __restrict__ bias, void* __restrict__ Cv,
    int K, int ldc, int bnPerXcd)
{
    __shared__ u16 As[128 * 64];
    __shared__ u16 Bs[128 * 64];
    const int t = threadIdx.x;
    const int lane = t & 63;
    const int w = t >> 6;
    const int wm = w >> 1, wn = w & 1;
    const int id = (int)blockIdx.x;
    const int xcd = id & 7, r = id >> 3;
    const int bm = (r / bnPerXcd) * 128;
    const int bn = (xcd * bnPerXcd + r % bnPerXcd) * 128;
    const int lr = lane & 15;
    const int lg = lane >> 4;
    const int swz = (lr & 7) << 4;          // fragment-read byte XOR

    f32x4 acc[4][4] = {};

    for (int k0 = 0; k0 < K; k0 += 64) {
        #pragma unroll
        for (int i = 0; i < 4; ++i) {
            int idx = t + i * 256;          // granule index 0..1023 (16B each)
            int row = idx >> 3;             // tile row 0..127
            int gsrc = (idx & 7) ^ (row & 7);  // pre-swizzled source granule
            gload_lds16((const char*)A + ((size_t)(bm + row) * K + k0 + gsrc * 8) * 2,
                        (char*)As + idx * 16);
            gload_lds16((const char*)B + ((size_t)(bn + row) * K + k0 + gsrc * 8) * 2,
                        (char*)Bs + idx * 16);
        }
        __syncthreads();
        #pragma unroll
        for (int kk = 0; kk < 2; ++kk) {
            bf16x8 af[4], bfr[4];
            #pragma unroll
            for (int m = 0; m < 4; ++m)
                af[m] = *(const bf16x8*)((const char*)As + (wm * 64 + m * 16 + lr) * 128 +
                                         ((kk * 64 + lg * 16) ^ swz));
            #pragma unroll
            for (int n = 0; n < 4; ++n)
                bfr[n] = *(const bf16x8*)((const char*)Bs + (wn * 64 + n * 16 + lr) * 128 +
                                          ((kk * 64 + lg * 16) ^ swz));
            #pragma unroll
            for (int m = 0; m < 4; ++m)
                #pragma unroll
                for (int n = 0; n < 4; ++n)
                    acc[m][n] = __builtin_amdgcn_mfma_f32_16x16x32_bf16(af[m], bfr[n], acc[m][n], 0, 0, 0);
        }
        __syncthreads();
    }

    #pragma unroll
    for (int n = 0; n < 4; ++n) {
        int col = bn + wn * 64 + n * 16 + lr;
        float bv = bias[col];
        #pragma unroll
        for (int m = 0; m < 4; ++m) {
            int row0 = bm + wm * 64 + m * 16 + lg * 4;
            #pragma unroll
            for (int r2 = 0; r2 < 4; ++r2) {
                float v = acc[m][n][r2] + bv;
                size_t idx = (size_t)(row0 + r2) * ldc + col;
                if (F32OUT) ((float*)Cv)[idx] = v;
                else        ((u16*)Cv)[idx] = f2bf(v);
            }
        }
    }
}

// ---------------- causal flash attention, v9 (unchanged from R10) ----------
__global__ __launch_bounds__(256, 2) void attn_fwd(
    const u16* __restrict__ QKV, u16* __restrict__ Om)
{
    constexpr int T = 2048, LD = 3072, DO = 1024;
    constexpr int PSTR = 72;
    constexpr float NEG = -3.0e38f;

    __shared__ __align__(16) u16 Ks[2][64 * 64];     // XOR-swizzled K rows
    __shared__ __align__(16) u16 Vt[2][64 * PSTR];   // Vt[d][kv]

    const int t = threadIdx.x, lane = t & 63, w = t >> 6;
    const int ql = lane & 31, hi = lane >> 5;

    const int id = (int)blockIdx.x;
    const int slot = id >> 6;
    const int bh = (id & 7) * 8 + ((id >> 3) & 7);
    const int q0 = (15 - slot) * 128;
    const int b = bh >> 4, h = bh & 15;
    const size_t rowbase = (size_t)b * T * LD + h * 64;
    const u16* Qm = QKV + rowbase;
    const u16* Km = QKV + rowbase + 1024;
    const u16* Vm = QKV + rowbase + 2048;
    const int nt = q0 / 64 + 2;                      // even (q0 % 128 == 0)

    const int qg = q0 + w * 32 + ql;
    const int qmax = q0 + w * 32 + 31;

    bf16x8 qf[4];
    {
        const u16* qp = Qm + (size_t)qg * LD + hi * 8;
        #pragma unroll
        for (int s = 0; s < 4; ++s) qf[s] = *(const bf16x8*)(qp + s * 16);
    }

    f32x16 oa[2] = {};
    float lsum = 0.f;

    const int krow = t >> 3, kslot = t & 7;
    const u16* kCur = Km + (size_t)krow * LD + 8 * (kslot ^ (krow & 7));
    const int kv2 = (t & 31) * 2, dd = (t >> 5) * 8;
    const u16* vCur = Vm + (size_t)kv2 * LD + dd;
    u16x8 vva, vvb;

    auto stageK = [&](int buf) {
        u16* dst = (u16*)Ks + buf * 4096 + t * 8;
        gload_lds16(kCur, dst);
        gload_lds16(kCur + 32 * LD, dst + 2048);
        kCur += 64 * LD;
    };
    auto loadV = [&]() {
        vva = *(const u16x8*)vCur;
        vvb = *(const u16x8*)(vCur + LD);
        vCur += 64 * LD;
    };
    auto writeVt = [&](int buf) {
        u32* vd = (u32*)((u16*)Vt + buf * (64 * PSTR) + dd * PSTR + kv2);
        #pragma unroll
        for (int j = 0; j < 8; ++j)
            vd[j * (PSTR / 2)] = (u32)vva[j] | ((u32)vvb[j] << 16);
    };

    stageK(0);
    loadV();
    writeVt(0);

    for (int it0 = 0; it0 < nt; it0 += 2) {
        #pragma unroll
        for (int half = 0; half < 2; ++half) {       // fully unrolled: BUF constant
            const int BUF = half;
            const int it = it0 + half;
            const int kv0 = it * 64;
            __syncthreads();

            const bool more = (it + 1 < nt);
            if (more) { stageK(BUF ^ 1); loadV(); }

            const bool a0  = kv0 <= qmax;
            const bool a0h = kv0 + 32 <= qmax;

            // ---- S^T = K Q^T ----
            f32x16 sa[2] = {};
            __builtin_amdgcn_s_setprio(1);
            #pragma unroll
            for (int n = 0; n < 2; ++n) {
                if (!(n ? a0h : a0)) continue;
                const int row = n * 32 + ql;
                const int swz = (row & 7) << 4;
                #pragma unroll
                for (int s = 0; s < 4; ++s) {
                    bf16x8 kf = *(const bf16x8*)((const char*)Ks + BUF * 8192 + row * 128 +
                                                 ((((s << 1) | hi) << 4) ^ swz));
                    sa[n] = mfma32(kf, qf[s], sa[n]);
                }
            }
            __builtin_amdgcn_s_setprio(0);

            // ---- softmax (no-max): P = exp2(S); sum; pack (T12) ----
            u32x4 pw[2][2];
            if (a0) {
                float rs = 0.f;
                #pragma unroll
                for (int n = 0; n < 2; ++n) {
                    if (n == 1 && !a0h) continue;
                    if (kv0 + n * 32 + 31 > q0 + w * 32) {
                        #pragma unroll
                        for (int r = 0; r < 16; ++r) {
                            int kvg = kv0 + n * 32 + (r & 3) + 8 * (r >> 2) + 4 * hi;
                            if (kvg > qg) sa[n][r] = NEG;
                        }
                    }
                    float pv[16];
                    #pragma unroll
                    for (int r = 0; r < 16; ++r)
                        pv[r] = __builtin_exp2f(sa[n][r]);
                    float s8[8];
                    #pragma unroll
                    for (int r = 0; r < 8; ++r) s8[r] = pv[r] + pv[r + 8];
                    rs += ((s8[0] + s8[4]) + (s8[1] + s8[5])) + ((s8[2] + s8[6]) + (s8[3] + s8[7]));
                    #pragma unroll
                    for (int s = 0; s < 2; ++s) {
                        u32 u0 = cvtpk_bf16(pv[8 * s + 0], pv[8 * s + 1]);
                        u32 u1 = cvtpk_bf16(pv[8 * s + 2], pv[8 * s + 3]);
                        u32 u2 = cvtpk_bf16(pv[8 * s + 4], pv[8 * s + 5]);
                        u32 u3 = cvtpk_bf16(pv[8 * s + 6], pv[8 * s + 7]);
                        plswap(u0, u2);
                        plswap(u1, u3);
                        pw[n][s] = u32x4{u0, u1, u2, u3};
                    }
                }
                rs += __shfl_xor(rs, 32);
                lsum += rs;
            }

            // ---- O^T += V^T P^T ----
            __builtin_amdgcn_s_setprio(1);
            #pragma unroll
            for (int dt = 0; dt < 2; ++dt) {
                const int vrow = dt * 32 + ql;
                #pragma unroll
                for (int n = 0; n < 2; ++n) {
                    if (!(n ? a0h : a0)) continue;
                    #pragma unroll
                    for (int s = 0; s < 2; ++s) {
                        bf16x8 vf = *(const bf16x8*)((const u16*)Vt + BUF * (64 * PSTR) +
                                                     vrow * PSTR + n * 32 + s * 16 + hi * 8);
                        oa[dt] = mfma32(vf, __builtin_bit_cast(bf16x8, pw[n][s]), oa[dt]);
                    }
                }
            }
            __builtin_amdgcn_s_setprio(0);

            if (more) writeVt(BUF ^ 1);
        }
    }

    // ---- epilogue: transpose O^T -> O via per-wave LDS region ----
    __syncthreads();
    u16* ot = ((u16*)Vt) + w * (32 * PSTR);
    const float inv = fastrcp(lsum);
    #pragma unroll
    for (int dt = 0; dt < 2; ++dt)
        #pragma unroll
        for (int r = 0; r < 16; ++r) {
            int d = dt * 32 + (r & 3) + 8 * (r >> 2) + 4 * hi;
            ot[ql * PSTR + d] = f2bf_fast(oa[dt][r] * inv);
        }
    const int lq = lane >> 1, hv = lane & 1;
    const size_t obase = (size_t)b * T * DO + h * 64;
    const u16* src = ot + lq * PSTR + hv * 32;
    u16* dst = Om + obase + (size_t)(q0 + w * 32 + lq) * DO + hv * 32;
    #pragma unroll
    for (int seg = 0; seg < 4; ++seg)
        *(u16x8*)(dst + seg * 8) = *(const u16x8*)(src + seg * 8);
}

extern "C" void kernel_launch(void* const* d_in, const int* in_sizes, int n_in,
                              void* d_out, int out_size, void* d_ws, size_t ws_size,
                              hipStream_t stream)
{
    const float* x  = (const float*)d_in[0];
    const float* Wq = (const float*)d_in[1];
    const float* bq = (const float*)d_in[2];
    const float* Wk = (const float*)d_in[3];
    const float* bk = (const float*)d_in[4];
    const float* Wv = (const float*)d_in[5];
    const float* bv = (const float*)d_in[6];
    const float* Wo = (const float*)d_in[7];
    const float* bo = (const float*)d_in[8];

    constexpr int T = 2048, D = 1024;
    constexpr size_t MT = (size_t)4 * T;   // 8192 rows

    const size_t NEED = (size_t)74 << 20;
    if (ws_size < NEED) return;

    char* ws = (char*)d_ws;
    u16* xb    = (u16*)(ws);                          // 16 MiB (dead after QKV GEMM)
    u16* Ob    = (u16*)(ws);                          // reuses xb region
    u16* Wqkvb = (u16*)(ws + ((size_t)16 << 20));     // 6 MiB
    u16* Wob   = (u16*)(ws + ((size_t)22 << 20));     // 2 MiB
    u16* QKVb  = (u16*)(ws + ((size_t)24 << 20));     // 48 MiB
    float* bqkv = (float*)(ws + ((size_t)72 << 20));  // 12 KiB

    int nx4 = (int)(MT * D / 4);
    cvt_f32_bf16<<<(nx4 + 255) / 256, 256, 0, stream>>>(x, xb, nx4, 1.0f);
    int nw4 = D * D / 4;
    cvt_f32_bf16<<<(nw4 + 255) / 256, 256, 0, stream>>>(Wq, Wqkvb, nw4, CSCALE);
    cvt_f32_bf16<<<(nw4 + 255) / 256, 256, 0, stream>>>(Wk, Wqkvb + (size_t)D * D, nw4, 1.0f);
    cvt_f32_bf16<<<(nw4 + 255) / 256, 256, 0, stream>>>(Wv, Wqkvb + (size_t)2 * D * D, nw4, 1.0f);
    cvt_f32_bf16<<<(nw4 + 255) / 256, 256, 0, stream>>>(Wo, Wob, nw4, 1.0f);
    build_bias<<<12, 256, 0, stream>>>(bq, bk, bv, bqkv);

    // fused QKV GEMM: [8192,1024] x [3072,1024]^T -> [8192,3072]
    gemm_bt<0><<<dim3(1536), 256, 0, stream>>>(xb, Wqkvb, bqkv, QKVb, D, 3072, 3);

    attn_fwd<<<dim3(1024), 256, 0, stream>>>(QKVb, Ob);

    // output projection: [8192,1024] x [1024,1024]^T -> [8192,1024] f32
    gemm_bt<1><<<dim3(512), 256, 0, stream>>>(Ob, Wob, bo, d_out, D, 1024, 1);
}